// Round 10
// baseline (265.832 us; speedup 1.0000x reference)
//
#include <hip/hip_runtime.h>

// GCN 2-layer forward — 4-dispatch pipeline.
// R10: sort chain (hist->scan->partition->bsort) folded INTO the gemm1
//   launch as co-scheduled blocks with device-scope spin barriers
//   (__hip_atomic acquire/release + __threadfence). Evidence: graph-captured
//   boundary ~1us (R6->R9 delta), grid.sync ~70us (R8) — so co-scheduling,
//   not mega-kernel, is the way to overlap.
//   L1 k_combo : blocks[0,ntile) gemm1 MFMA bf16 | blocks[ntile,ntile+NS)
//                hist -> (s==0) scan -> partition -> (s<NB) bsort
//   L2 k_pull1 : out1(bf16x2) = normalized gather-sum of h rows (8-unroll)
//   L3 k_gemm2 : h2 = relu(out1+b1) @ W2 (bf16)
//   L4 k_pull2 : layer-2 gather + fused log_softmax

typedef unsigned int uint32;
typedef unsigned short u16;
typedef __attribute__((ext_vector_type(8))) short bf16x8;
typedef __attribute__((ext_vector_type(4))) float f32x4;

#define NBMAX 1024
#define CHUNK 4096

__device__ inline u16 bf16rn(float f) {
    unsigned u = __float_as_uint(f);
    return (u16)((u + 0x7fffu + ((u >> 16) & 1u)) >> 16);
}

__device__ inline void bffma(float2& a, float w, uint32 u) {
    a.x = fmaf(w, __uint_as_float(u << 16), a.x);
    a.y = fmaf(w, __uint_as_float(u & 0xffff0000u), a.y);
}

// ctl[0] = ctr0 (hist done), ctl[1] = flag (scan done), ctl[2] = ctr2 (partition done)
__global__ __launch_bounds__(256) void k_combo(
    const float* __restrict__ x, const float* __restrict__ W1,
    const int* __restrict__ src, const int* __restrict__ dstv,
    int* __restrict__ bcnt, int* __restrict__ ctl,
    int* __restrict__ bbase, int* __restrict__ bfill,
    int2* __restrict__ tmp, int* __restrict__ ssrc,
    int* __restrict__ rs, float* __restrict__ dinv,
    u16* __restrict__ h, int N, int E, int NB, int ntile, int NS)
{
    __shared__ __align__(16) unsigned char smem[128 * 136 * 2];  // 34816 B union
    int t = threadIdx.x;

    if ((int)blockIdx.x >= ntile) {
        // =================== sort path =====================================
        int s = blockIdx.x - ntile;
        int e0 = s * CHUNK, e1 = min(e0 + CHUNK, E);
        int* cntL = (int*)smem;            // [NBMAX]
        int* baseL = cntL + NBMAX;         // [NBMAX]

        // ---- hist: LDS counts -> global bcnt ------------------------------
        for (int i = t; i < NB; i += 256) cntL[i] = 0;
        __syncthreads();
        for (int e = e0 + t; e < e1; e += 256)
            atomicAdd(&cntL[dstv[e] >> 8], 1);
        __syncthreads();
        for (int i = t; i < NB; i += 256)
            if (cntL[i]) atomicAdd(&bcnt[i], cntL[i]);
        __syncthreads();
        if (t == 0)
            __hip_atomic_fetch_add(&ctl[0], 1, __ATOMIC_ACQ_REL,
                                   __HIP_MEMORY_SCOPE_AGENT);

        // ---- scan (sort block 0 only) -------------------------------------
        if (s == 0) {
            if (t == 0)
                while (__hip_atomic_load(&ctl[0], __ATOMIC_ACQUIRE,
                                         __HIP_MEMORY_SCOPE_AGENT) < NS)
                    __builtin_amdgcn_s_sleep(8);
            __syncthreads();
            int* sc = baseL;  // reuse baseL region for the scan scratch
            int v[4];
            int sum = 0;
            #pragma unroll
            for (int i = 0; i < 4; ++i) {
                int idx = t * 4 + i;
                v[i] = (idx < NB) ? bcnt[idx] : 0;
                sum += v[i];
            }
            sc[t] = sum;
            __syncthreads();
            for (int off = 1; off < 256; off <<= 1) {
                int u = (t >= off) ? sc[t - off] : 0;
                __syncthreads();
                sc[t] += u;
                __syncthreads();
            }
            int excl = (t > 0) ? sc[t - 1] : 0;
            #pragma unroll
            for (int i = 0; i < 4; ++i) {
                int idx = t * 4 + i;
                if (idx < NB) { bbase[idx] = excl; bfill[idx] = 0; }
                excl += v[i];
            }
            if (t == 0) bbase[NB] = E;
            __threadfence();
            __syncthreads();
            if (t == 0)
                __hip_atomic_store(&ctl[1], 1, __ATOMIC_RELEASE,
                                   __HIP_MEMORY_SCOPE_AGENT);
        }

        // ---- partition: all sort blocks wait for scan ---------------------
        if (t == 0)
            while (__hip_atomic_load(&ctl[1], __ATOMIC_ACQUIRE,
                                     __HIP_MEMORY_SCOPE_AGENT) == 0)
                __builtin_amdgcn_s_sleep(8);
        __syncthreads();
        // cntL still holds this chunk's counts (LDS persisted)
        for (int i = t; i < NB; i += 256) {
            int c = cntL[i];
            baseL[i] = c ? bbase[i] + atomicAdd(&bfill[i], c) : 0;
            cntL[i] = 0;
        }
        __syncthreads();
        for (int e = e0 + t; e < e1; e += 256) {
            int sv = src[e], d = dstv[e];
            int b = d >> 8;
            int r = atomicAdd(&cntL[b], 1);
            tmp[baseL[b] + r] = make_int2(sv, d);
        }
        __threadfence();
        __syncthreads();
        if (t == 0)
            __hip_atomic_fetch_add(&ctl[2], 1, __ATOMIC_ACQ_REL,
                                   __HIP_MEMORY_SCOPE_AGENT);

        // ---- bsort: blocks s < NB, one bucket each ------------------------
        if (s >= NB) return;
        if (t == 0)
            while (__hip_atomic_load(&ctl[2], __ATOMIC_ACQUIRE,
                                     __HIP_MEMORY_SCOPE_AGENT) < NS)
                __builtin_amdgcn_s_sleep(8);
        __syncthreads();
        int* cnt = cntL;        // [256]
        int* ofs = cntL + 256;  // [256]
        int base = bbase[s];
        int endb = bbase[s + 1];
        int node0 = s << 8;
        cnt[t] = 0;
        __syncthreads();
        for (int i = base + t; i < endb; i += 256)
            atomicAdd(&cnt[tmp[i].y & 255], 1);
        __syncthreads();
        int v = cnt[t];
        __syncthreads();
        for (int off = 1; off < 256; off <<= 1) {
            int u = (t >= off) ? cnt[t - off] : 0;
            __syncthreads();
            cnt[t] += u;
            __syncthreads();
        }
        int node = node0 + t;
        if (node < N) {
            dinv[node] = rsqrtf(fmaxf((float)v, 1.0f));
            rs[node] = base + cnt[t];
        }
        ofs[t] = base + cnt[t] - v;
        __syncthreads();
        for (int i = base + t; i < endb; i += 256) {
            int2 rec = tmp[i];
            int pos = atomicAdd(&ofs[rec.y & 255], 1);
            ssrc[pos] = rec.x;
        }
        return;
    }

    // =================== gemm1 path ========================================
    u16* Wl = (u16*)smem;  // [n][k] pitch 136 (2-way bank aliasing: free)
    const float4* Wg4 = (const float4*)W1;
    for (int g = t; g < 128 * 32; g += 256) {
        int k = g >> 5, n4 = (g & 31) * 4;
        float4 v = Wg4[g];
        Wl[(n4 + 0) * 136 + k] = bf16rn(v.x);
        Wl[(n4 + 1) * 136 + k] = bf16rn(v.y);
        Wl[(n4 + 2) * 136 + k] = bf16rn(v.z);
        Wl[(n4 + 3) * 136 + k] = bf16rn(v.w);
    }
    __syncthreads();

    int wave = t >> 6, lane = t & 63;
    int quad = lane >> 4, ln = lane & 15;
    int rowbase = blockIdx.x * 64 + wave * 16;
    int rclamp = min(rowbase + ln, N - 1);

    f32x4 acc[8];
    #pragma unroll
    for (int ct = 0; ct < 8; ++ct) acc[ct] = (f32x4){0.f, 0.f, 0.f, 0.f};

    #pragma unroll
    for (int q = 0; q < 4; ++q) {
        const float4* xr = (const float4*)(x + (size_t)rclamp * 128 + q * 32 + quad * 8);
        float4 a0 = xr[0], a1 = xr[1];
        bf16x8 afr;
        afr[0] = (short)bf16rn(a0.x); afr[1] = (short)bf16rn(a0.y);
        afr[2] = (short)bf16rn(a0.z); afr[3] = (short)bf16rn(a0.w);
        afr[4] = (short)bf16rn(a1.x); afr[5] = (short)bf16rn(a1.y);
        afr[6] = (short)bf16rn(a1.z); afr[7] = (short)bf16rn(a1.w);
        #pragma unroll
        for (int ct = 0; ct < 8; ++ct) {
            bf16x8 bfr = *(const bf16x8*)&Wl[(ct * 16 + ln) * 136 + q * 32 + quad * 8];
            acc[ct] = __builtin_amdgcn_mfma_f32_16x16x32_bf16(afr, bfr, acc[ct], 0, 0, 0);
        }
    }
    #pragma unroll
    for (int i = 0; i < 4; ++i) {
        int r = rowbase + quad * 4 + i;
        if (r < N) {
            u16* hp = h + (size_t)r * 128 + ln;
            #pragma unroll
            for (int ct = 0; ct < 8; ++ct)
                hp[ct * 16] = bf16rn(acc[ct][i]);
        }
    }
}

// ---- L2: pull1 — out1[n,:] (bf16x2) = sum_e w_e * h[src_e,:], 8-unroll ----
__global__ __launch_bounds__(256) void k_pull1(
    const int* __restrict__ rs, const int* __restrict__ ssrc,
    const float* __restrict__ dinv, const uint32* __restrict__ h,
    uint32* __restrict__ out1, int N)
{
    int n = (blockIdx.x * 256 + threadIdx.x) >> 6;
    if (n >= N) return;
    int lane = threadIdx.x & 63;
    int start = __builtin_amdgcn_readfirstlane((n == 0) ? 0 : rs[n - 1]);
    int end   = __builtin_amdgcn_readfirstlane(rs[n]);
    float dn = dinv[n];
    float2 a[8];
    #pragma unroll
    for (int i = 0; i < 8; ++i) a[i] = (float2){0.f, 0.f};
    int j = start;
    for (; j + 7 < end; j += 8) {
        int si[8];
        uint32 u[8];
        float w[8];
        #pragma unroll
        for (int i = 0; i < 8; ++i)
            si[i] = __builtin_amdgcn_readfirstlane(ssrc[j + i]);
        #pragma unroll
        for (int i = 0; i < 8; ++i)
            u[i] = h[(size_t)si[i] * 64 + lane];
        #pragma unroll
        for (int i = 0; i < 8; ++i)
            w[i] = dn * dinv[si[i]];
        #pragma unroll
        for (int i = 0; i < 8; ++i)
            bffma(a[i], w[i], u[i]);
    }
    for (; j < end; ++j) {
        int s0 = __builtin_amdgcn_readfirstlane(ssrc[j]);
        bffma(a[0], dn * dinv[s0], h[(size_t)s0 * 64 + lane]);
    }
    float rx = ((a[0].x + a[1].x) + (a[2].x + a[3].x)) +
               ((a[4].x + a[5].x) + (a[6].x + a[7].x));
    float ry = ((a[0].y + a[1].y) + (a[2].y + a[3].y)) +
               ((a[4].y + a[5].y) + (a[6].y + a[7].y));
    out1[(size_t)n * 64 + lane] = ((uint32)bf16rn(ry) << 16) | bf16rn(rx);
}

// ---- L3: gemm2 — h2[N,16](bf16) = relu(out1+b1) @ W2 ----------------------
__global__ __launch_bounds__(256) void k_gemm2(
    const uint32* __restrict__ out1, const float* __restrict__ b1,
    const float* __restrict__ W2, u16* __restrict__ h2, int N)
{
    __shared__ float W2T[16 * 132];
    __shared__ float b1l[128];
    __shared__ float al[32 * 132];
    int t = threadIdx.x;
    int row0 = blockIdx.x * 32;

    for (int g = t; g < 2048; g += 256) {
        int k = g >> 4, f = g & 15;
        W2T[f * 132 + k] = W2[g];
    }
    if (t < 128) b1l[t] = b1[t];
    __syncthreads();

    float4* al4 = (float4*)al;
    const uint4* o4 = (const uint4*)out1;
    for (int g = t; g < 32 * 16; g += 256) {
        int r = g >> 4, k8 = g & 15;
        uint4 u = {0u, 0u, 0u, 0u};
        if (row0 + r < N) u = o4[(size_t)(row0 + r) * 16 + k8];
        const float* bb = &b1l[k8 * 8];
        float4 v0, v1;
        v0.x = fmaxf(__uint_as_float(u.x << 16)         + bb[0], 0.f);
        v0.y = fmaxf(__uint_as_float(u.x & 0xffff0000u) + bb[1], 0.f);
        v0.z = fmaxf(__uint_as_float(u.y << 16)         + bb[2], 0.f);
        v0.w = fmaxf(__uint_as_float(u.y & 0xffff0000u) + bb[3], 0.f);
        v1.x = fmaxf(__uint_as_float(u.z << 16)         + bb[4], 0.f);
        v1.y = fmaxf(__uint_as_float(u.z & 0xffff0000u) + bb[5], 0.f);
        v1.z = fmaxf(__uint_as_float(u.w << 16)         + bb[6], 0.f);
        v1.w = fmaxf(__uint_as_float(u.w & 0xffff0000u) + bb[7], 0.f);
        al4[r * 33 + k8 * 2]     = v0;
        al4[r * 33 + k8 * 2 + 1] = v1;
    }
    __syncthreads();

    int f = t & 15, r0 = t >> 4;
    const float4* W4 = (const float4*)W2T;
    float acc0 = 0.f, acc1 = 0.f;
    #pragma unroll 8
    for (int k4 = 0; k4 < 32; ++k4) {
        float4 w  = W4[f * 33 + k4];
        float4 x0 = al4[r0 * 33 + k4];
        float4 x1 = al4[(r0 + 16) * 33 + k4];
        acc0 = fmaf(x0.x, w.x, acc0); acc0 = fmaf(x0.y, w.y, acc0);
        acc0 = fmaf(x0.z, w.z, acc0); acc0 = fmaf(x0.w, w.w, acc0);
        acc1 = fmaf(x1.x, w.x, acc1); acc1 = fmaf(x1.y, w.y, acc1);
        acc1 = fmaf(x1.z, w.z, acc1); acc1 = fmaf(x1.w, w.w, acc1);
    }
    if (row0 + r0 < N)      h2[(size_t)(row0 + r0) * 16 + f] = bf16rn(acc0);
    if (row0 + r0 + 16 < N) h2[(size_t)(row0 + r0 + 16) * 16 + f] = bf16rn(acc1);
}

// ---- L4: pull2 + log_softmax (8 lanes/row, 2 classes/lane) ----------------
__global__ __launch_bounds__(256) void k_pull2(
    const int* __restrict__ rs, const int* __restrict__ ssrc,
    const float* __restrict__ dinv, const uint32* __restrict__ h2,
    const float* __restrict__ b2, float* __restrict__ out, int N)
{
    int idx = blockIdx.x * 256 + threadIdx.x;
    int n = idx >> 3;
    if (n >= N) return;
    int c = idx & 7;
    int start = (n == 0) ? 0 : rs[n - 1];
    int end = rs[n];
    float dn = dinv[n];
    float acc0 = 0.f, acc1 = 0.f;
    for (int j = start; j < end; ++j) {
        int s = ssrc[j];
        float w = dn * dinv[s];
        uint32 u = h2[(size_t)s * 8 + c];
        acc0 = fmaf(w, __uint_as_float(u << 16), acc0);
        acc1 = fmaf(w, __uint_as_float(u & 0xffff0000u), acc1);
    }
    float v0 = acc0 + b2[2 * c];
    float v1 = acc1 + b2[2 * c + 1];
    float m = fmaxf(v0, v1);
    #pragma unroll
    for (int off = 1; off < 8; off <<= 1) m = fmaxf(m, __shfl_xor(m, off));
    float s = expf(v0 - m) + expf(v1 - m);
    #pragma unroll
    for (int off = 1; off < 8; off <<= 1) s += __shfl_xor(s, off);
    float ls = logf(s);
    float2 r = {v0 - m - ls, v1 - m - ls};
    ((float2*)out)[(size_t)n * 8 + c] = r;
}

extern "C" void kernel_launch(void* const* d_in, const int* in_sizes, int n_in,
                              void* d_out, int out_size, void* d_ws, size_t ws_size,
                              hipStream_t stream) {
    const float* x  = (const float*)d_in[0];
    const int*   ei = (const int*)d_in[1];
    const float* W1 = (const float*)d_in[2];
    const float* b1 = (const float*)d_in[3];
    const float* W2 = (const float*)d_in[4];
    const float* b2 = (const float*)d_in[5];
    float* outp = (float*)d_out;

    const int E = in_sizes[1] / 2;
    const int N = in_sizes[0] / 128;
    const int NB = (N + 255) >> 8;
    const int ntile = (N + 63) / 64;
    int NS = (E + CHUNK - 1) / CHUNK;
    if (NS < NB) NS = NB;
    const int* src  = ei;
    const int* dstv = ei + E;

    const int Npad = (N + 255) & ~255;
    const int Epad = (E + 255) & ~255;
    int*   bcnt  = (int*)d_ws;                      // [NBMAX]
    int*   ctl   = bcnt + NBMAX;                    // [8]
    int*   bbase = ctl + 8;                         // [NBMAX+1] (+pad)
    int*   bfill = bbase + NBMAX + 248;             // [NBMAX]
    int*   rs    = bfill + NBMAX;                   // [Npad]
    float* dinv  = (float*)(rs + Npad);             // [Npad]
    int2*  tmp   = (int2*)(dinv + Npad);            // [Epad]
    int*   ssrc  = (int*)(tmp + Epad);              // [Epad]
    u16*   h     = (u16*)(ssrc + Epad);             // N*128 bf16 (aliased h2)
    uint32* out1 = (uint32*)(h + (size_t)N * 128);  // N*64 packed bf16x2
    u16*   h2    = h;

    // zero bcnt + ctl (4128 B) — everything else is written before read
    hipMemsetAsync(bcnt, 0, (NBMAX + 8) * sizeof(int), stream);

    k_combo<<<ntile + NS, 256, 0, stream>>>(x, W1, src, dstv, bcnt, ctl, bbase,
                                            bfill, tmp, ssrc, rs, dinv, h,
                                            N, E, NB, ntile, NS);
    k_pull1<<<(N * 64 + 255) / 256, 256, 0, stream>>>(rs, ssrc, dinv,
                                                      (const uint32*)h, out1, N);
    k_gemm2<<<(N + 31) / 32, 256, 0, stream>>>(out1, b1, W2, h2, N);
    k_pull2<<<(N * 8 + 255) / 256, 256, 0, stream>>>(rs, ssrc, dinv,
                                                     (const uint32*)h2, b2, outp, N);
}